// Round 2
// baseline (322.010 us; speedup 1.0000x reference)
//
#include <hip/hip_runtime.h>
#include <math.h>

#define BLK 256
#define EPS_EYE 1e-7f

// Compute one 3x3 covariance (upper-tri symmetric, +eps*I) from quaternion
// (x,y,z,w) and pre-exponentiated... no: sx,sy,sz are raw scalings; exp here.
__device__ __forceinline__ void cov_point(float x, float y, float z, float w,
                                          float a, float b, float c,
                                          float* __restrict__ o /*9 floats*/)
{
    const float inv = 1.0f / sqrtf(x * x + y * y + z * z + w * w);
    x *= inv; y *= inv; z *= inv; w *= inv;

    const float sx = expf(a);
    const float sy = expf(b);
    const float sz = expf(c);

    const float R00 = 1.0f - 2.0f * (y * y + z * z);
    const float R01 = 2.0f * (x * y - w * z);
    const float R02 = 2.0f * (x * z + w * y);
    const float R10 = 2.0f * (x * y + w * z);
    const float R11 = 1.0f - 2.0f * (x * x + z * z);
    const float R12 = 2.0f * (y * z - w * x);
    const float R20 = 2.0f * (x * z - w * y);
    const float R21 = 2.0f * (y * z + w * x);
    const float R22 = 1.0f - 2.0f * (x * x + y * y);

    const float l00 = R00 * sx, l01 = R01 * sy, l02 = R02 * sz;
    const float l10 = R10 * sx, l11 = R11 * sy, l12 = R12 * sz;
    const float l20 = R20 * sx, l21 = R21 * sy, l22 = R22 * sz;

    const float c00 = l00 * l00 + l01 * l01 + l02 * l02 + EPS_EYE;
    const float c01 = l00 * l10 + l01 * l11 + l02 * l12;
    const float c02 = l00 * l20 + l01 * l21 + l02 * l22;
    const float c11 = l10 * l10 + l11 * l11 + l12 * l12 + EPS_EYE;
    const float c12 = l10 * l20 + l11 * l21 + l12 * l22;
    const float c22 = l20 * l20 + l21 * l21 + l22 * l22 + EPS_EYE;

    o[0] = c00; o[1] = c01; o[2] = c02;
    o[3] = c01; o[4] = c11; o[5] = c12;
    o[6] = c02; o[7] = c12; o[8] = c22;
}

// 4 points per thread: all global IO is aligned float4, no LDS, no barriers.
__global__ __launch_bounds__(BLK) void gaussian_cov_kernel(
    const float4* __restrict__ s4,   // scaling, 3 float4 per thread-group-of-4-pts
    const float4* __restrict__ q4,   // rotation, 4 float4
    float4* __restrict__ o4,         // out, 9 float4
    int nQuads)                      // N/4
{
    const int t = blockIdx.x * BLK + threadIdx.x;
    if (t >= nQuads) return;

    // Issue all loads up front (7 dwordx4) so they overlap.
    const float4 s0 = s4[3 * t + 0];
    const float4 s1 = s4[3 * t + 1];
    const float4 s2 = s4[3 * t + 2];
    const float4 q0 = q4[4 * t + 0];
    const float4 q1 = q4[4 * t + 1];
    const float4 q2 = q4[4 * t + 2];
    const float4 q3 = q4[4 * t + 3];

    float o[36];
    cov_point(q0.x, q0.y, q0.z, q0.w, s0.x, s0.y, s0.z, o + 0);
    cov_point(q1.x, q1.y, q1.z, q1.w, s0.w, s1.x, s1.y, o + 9);
    cov_point(q2.x, q2.y, q2.z, q2.w, s1.z, s1.w, s2.x, o + 18);
    cov_point(q3.x, q3.y, q3.z, q3.w, s2.y, s2.z, s2.w, o + 27);

    float4* dst = o4 + (long long)9 * t;
#pragma unroll
    for (int j = 0; j < 9; ++j) {
        dst[j] = make_float4(o[4 * j + 0], o[4 * j + 1], o[4 * j + 2], o[4 * j + 3]);
    }
}

// Scalar tail kernel for N % 4 != 0 (N=5M is divisible by 4; kept for safety).
__global__ void gaussian_cov_tail(
    const float* __restrict__ scaling,
    const float* __restrict__ rotation,
    float* __restrict__ out,
    int start, int N)
{
    const int i = start + blockIdx.x * blockDim.x + threadIdx.x;
    if (i >= N) return;
    float o[9];
    cov_point(rotation[4 * i + 0], rotation[4 * i + 1], rotation[4 * i + 2], rotation[4 * i + 3],
              scaling[3 * i + 0], scaling[3 * i + 1], scaling[3 * i + 2], o);
#pragma unroll
    for (int j = 0; j < 9; ++j) out[9 * i + j] = o[j];
}

extern "C" void kernel_launch(void* const* d_in, const int* in_sizes, int n_in,
                              void* d_out, int out_size, void* d_ws, size_t ws_size,
                              hipStream_t stream) {
    const float* scaling  = (const float*)d_in[0];
    const float* rotation = (const float*)d_in[1];
    float* out = (float*)d_out;
    const int N = in_sizes[0] / 3;
    const int nQuads = N / 4;

    if (nQuads > 0) {
        const int blocks = (nQuads + BLK - 1) / BLK;
        gaussian_cov_kernel<<<blocks, BLK, 0, stream>>>(
            (const float4*)scaling, (const float4*)rotation, (float4*)out, nQuads);
    }
    const int done = nQuads * 4;
    if (done < N) {
        const int rem = N - done;
        gaussian_cov_tail<<<(rem + 63) / 64, 64, 0, stream>>>(scaling, rotation, out, done, N);
    }
}

// Round 3
// 278.734 us; speedup vs baseline: 1.1553x; 1.1553x over previous
//
#include <hip/hip_runtime.h>
#include <math.h>

#define BLK 256          // threads per block
#define PTS 512          // points per block tile (2 per thread)
#define EPS_EYE 1e-7f

// Lesson from R2: multi-point-per-thread AoS access (lane stride 48/64/144 B)
// collapses to 2.3 TB/s — request-rate bound, not HBM bound. Everything here
// is lane-contiguous float4 at the global level; strided accesses live in LDS
// where stride-3/stride-9 over 32 banks is a free 2-way alias (gcd = 1).
__global__ __launch_bounds__(BLK) void gaussian_cov_kernel(
    const float* __restrict__ scaling,
    const float* __restrict__ rotation,
    float* __restrict__ out,
    int N)
{
    __shared__ __align__(16) float lds_s[PTS * 3];   // 6 KB
    __shared__ __align__(16) float lds_o[PTS * 9];   // 18 KB

    const int tid = threadIdx.x;
    const long long tileBase = (long long)blockIdx.x * PTS;
    const int nPts = min(PTS, (int)((long long)N - tileBase));
    const int nSF = nPts * 3;

    // ---- Phase 1: stage scaling, coalesced f4 global -> f4 LDS ----
    // tileBase*3 floats = 6144 B * blockIdx -> 16B aligned.
    {
        const float4* __restrict__ s4 = (const float4*)(scaling + tileBase * 3);
        float4* __restrict__ l4 = (float4*)lds_s;
        const int nS4 = nSF >> 2;
        for (int i = tid; i < nS4; i += BLK) l4[i] = s4[i];
        for (int i = (nS4 << 2) + tid; i < nSF; i += BLK)
            lds_s[i] = scaling[tileBase * 3 + i];
    }
    __syncthreads();

    // ---- Phase 2: per-point math; rotation loaded directly (lane-contiguous f4) ----
    const float4* __restrict__ q4 = (const float4*)rotation;
#pragma unroll
    for (int k = 0; k < PTS / BLK; ++k) {
        const int p = k * BLK + tid;
        if (p < nPts) {
            const float4 q = q4[tileBase + p];
            float x = q.x, y = q.y, z = q.z, w = q.w;
            const float inv = 1.0f / sqrtf(x * x + y * y + z * z + w * w);
            x *= inv; y *= inv; z *= inv; w *= inv;

            const float sx = expf(lds_s[p * 3 + 0]);
            const float sy = expf(lds_s[p * 3 + 1]);
            const float sz = expf(lds_s[p * 3 + 2]);

            const float R00 = 1.0f - 2.0f * (y * y + z * z);
            const float R01 = 2.0f * (x * y - w * z);
            const float R02 = 2.0f * (x * z + w * y);
            const float R10 = 2.0f * (x * y + w * z);
            const float R11 = 1.0f - 2.0f * (x * x + z * z);
            const float R12 = 2.0f * (y * z - w * x);
            const float R20 = 2.0f * (x * z - w * y);
            const float R21 = 2.0f * (y * z + w * x);
            const float R22 = 1.0f - 2.0f * (x * x + y * y);

            const float l00 = R00 * sx, l01 = R01 * sy, l02 = R02 * sz;
            const float l10 = R10 * sx, l11 = R11 * sy, l12 = R12 * sz;
            const float l20 = R20 * sx, l21 = R21 * sy, l22 = R22 * sz;

            const float c00 = l00 * l00 + l01 * l01 + l02 * l02 + EPS_EYE;
            const float c01 = l00 * l10 + l01 * l11 + l02 * l12;
            const float c02 = l00 * l20 + l01 * l21 + l02 * l22;
            const float c11 = l10 * l10 + l11 * l11 + l12 * l12 + EPS_EYE;
            const float c12 = l10 * l20 + l11 * l21 + l12 * l22;
            const float c22 = l20 * l20 + l21 * l21 + l22 * l22 + EPS_EYE;

            float* __restrict__ o = lds_o + p * 9;   // stride-9: free 2-way alias
            o[0] = c00; o[1] = c01; o[2] = c02;
            o[3] = c01; o[4] = c11; o[5] = c12;
            o[6] = c02; o[7] = c12; o[8] = c22;
        }
    }
    __syncthreads();

    // ---- Phase 3: coalesced f4 LDS -> global store ----
    // tileBase*9 floats = 18432 B * blockIdx -> 16B aligned.
    {
        const int nOF = nPts * 9;
        const int nO4 = nOF >> 2;
        float4* __restrict__ dst = (float4*)(out + tileBase * 9);
        const float4* __restrict__ lo4 = (const float4*)lds_o;
        for (int i = tid; i < nO4; i += BLK) dst[i] = lo4[i];
        for (int i = (nO4 << 2) + tid; i < nOF; i += BLK)
            out[tileBase * 9 + i] = lds_o[i];
    }
}

extern "C" void kernel_launch(void* const* d_in, const int* in_sizes, int n_in,
                              void* d_out, int out_size, void* d_ws, size_t ws_size,
                              hipStream_t stream) {
    const float* scaling  = (const float*)d_in[0];
    const float* rotation = (const float*)d_in[1];
    float* out = (float*)d_out;
    const int N = in_sizes[0] / 3;
    const int blocks = (N + PTS - 1) / PTS;
    gaussian_cov_kernel<<<blocks, BLK, 0, stream>>>(scaling, rotation, out, N);
}

// Round 5
// 264.491 us; speedup vs baseline: 1.2175x; 1.0538x over previous
//
#include <hip/hip_runtime.h>
#include <math.h>

#define BLK 256          // threads per block
#define PTS 512          // points per block tile (2 per thread)
#define EPS_EYE 1e-7f

// Native clang vector type — required by __builtin_nontemporal_load/store
// (HIP_vector_type float4 is a struct and is rejected).
typedef float f32x4 __attribute__((ext_vector_type(4)));

// R2 lesson: multi-point/thread AoS global access (lane stride 48/64/144 B)
// collapses to 2.3 TB/s. All global IO here is lane-contiguous 16B vectors;
// transposes go through LDS (stride-3/9 = free 2-way bank alias, measured 0
// conflicts). R5: R4 retry with native vector type for nontemporal builtins.

__device__ __forceinline__ void cov_math(f32x4 q, float a, float b, float c,
                                         float* __restrict__ o /*9*/)
{
    float x = q.x, y = q.y, z = q.z, w = q.w;
    const float inv = 1.0f / sqrtf(x * x + y * y + z * z + w * w);
    x *= inv; y *= inv; z *= inv; w *= inv;

    const float sx = expf(a);
    const float sy = expf(b);
    const float sz = expf(c);

    const float R00 = 1.0f - 2.0f * (y * y + z * z);
    const float R01 = 2.0f * (x * y - w * z);
    const float R02 = 2.0f * (x * z + w * y);
    const float R10 = 2.0f * (x * y + w * z);
    const float R11 = 1.0f - 2.0f * (x * x + z * z);
    const float R12 = 2.0f * (y * z - w * x);
    const float R20 = 2.0f * (x * z - w * y);
    const float R21 = 2.0f * (y * z + w * x);
    const float R22 = 1.0f - 2.0f * (x * x + y * y);

    const float l00 = R00 * sx, l01 = R01 * sy, l02 = R02 * sz;
    const float l10 = R10 * sx, l11 = R11 * sy, l12 = R12 * sz;
    const float l20 = R20 * sx, l21 = R21 * sy, l22 = R22 * sz;

    o[0] = l00 * l00 + l01 * l01 + l02 * l02 + EPS_EYE;
    o[1] = l00 * l10 + l01 * l11 + l02 * l12;
    o[2] = l00 * l20 + l01 * l21 + l02 * l22;
    o[3] = o[1];
    o[4] = l10 * l10 + l11 * l11 + l12 * l12 + EPS_EYE;
    o[5] = l10 * l20 + l11 * l21 + l12 * l22;
    o[6] = o[2];
    o[7] = o[5];
    o[8] = l20 * l20 + l21 * l21 + l22 * l22 + EPS_EYE;
}

__global__ __launch_bounds__(BLK) void gaussian_cov_kernel(
    const float* __restrict__ scaling,
    const float* __restrict__ rotation,
    float* __restrict__ out,
    int N)
{
    __shared__ __align__(16) float lds_s[PTS * 3];   // 6 KB
    __shared__ __align__(16) float lds_o[PTS * 9];   // 18 KB

    const int tid = threadIdx.x;
    const long long tileBase = (long long)blockIdx.x * PTS;
    const int nPts = min(PTS, (int)((long long)N - tileBase));
    const f32x4* __restrict__ q4 = (const f32x4*)rotation;

    if (nPts == PTS) {
        // ================= FAST PATH (all but the last block) =================
        // Phase 1: stage scaling. PTS*3/4 = 384 vectors for 256 threads.
        {
            const f32x4* __restrict__ s4 = (const f32x4*)(scaling + tileBase * 3);
            f32x4* __restrict__ l4 = (f32x4*)lds_s;
            const bool h = tid < (PTS * 3 / 4 - BLK);          // 128
            f32x4 a = __builtin_nontemporal_load(&s4[tid]);
            f32x4 b;
            if (h) b = __builtin_nontemporal_load(&s4[BLK + tid]);
            l4[tid] = a;
            if (h) l4[BLK + tid] = b;
        }
        __syncthreads();

        // Phase 2: two points per thread; rotation loaded lane-contiguous.
#pragma unroll
        for (int k = 0; k < PTS / BLK; ++k) {
            const int p = k * BLK + tid;
            const f32x4 q = __builtin_nontemporal_load(&q4[tileBase + p]);
            float o[9];
            cov_math(q, lds_s[p * 3 + 0], lds_s[p * 3 + 1], lds_s[p * 3 + 2], o);
            float* __restrict__ lo = lds_o + p * 9;   // stride-9: free alias
#pragma unroll
            for (int j = 0; j < 9; ++j) lo[j] = o[j];
        }
        __syncthreads();

        // Phase 3: PTS*9/4 = 1152 vectors = 4*256 + 128. Batch all LDS reads,
        // then issue all stores (compile-time trip counts -> full MLP).
        {
            const f32x4* __restrict__ lo4 = (const f32x4*)lds_o;
            f32x4* __restrict__ dst = (f32x4*)(out + tileBase * 9);
            const bool h = tid < (PTS * 9 / 4 - 4 * BLK);      // 128
            f32x4 r0 = lo4[tid];
            f32x4 r1 = lo4[tid + 1 * BLK];
            f32x4 r2 = lo4[tid + 2 * BLK];
            f32x4 r3 = lo4[tid + 3 * BLK];
            f32x4 r4;
            if (h) r4 = lo4[tid + 4 * BLK];
            __builtin_nontemporal_store(r0, &dst[tid]);
            __builtin_nontemporal_store(r1, &dst[tid + 1 * BLK]);
            __builtin_nontemporal_store(r2, &dst[tid + 2 * BLK]);
            __builtin_nontemporal_store(r3, &dst[tid + 3 * BLK]);
            if (h) __builtin_nontemporal_store(r4, &dst[tid + 4 * BLK]);
        }
    } else {
        // ================= GENERIC TAIL PATH (last block only) ================
        const int nSF = nPts * 3;
        {
            const f32x4* __restrict__ s4 = (const f32x4*)(scaling + tileBase * 3);
            f32x4* __restrict__ l4 = (f32x4*)lds_s;
            const int nS4 = nSF >> 2;
            for (int i = tid; i < nS4; i += BLK) l4[i] = s4[i];
            for (int i = (nS4 << 2) + tid; i < nSF; i += BLK)
                lds_s[i] = scaling[tileBase * 3 + i];
        }
        __syncthreads();

        for (int k = 0; k < PTS / BLK; ++k) {
            const int p = k * BLK + tid;
            if (p < nPts) {
                const f32x4 q = q4[tileBase + p];
                float o[9];
                cov_math(q, lds_s[p * 3 + 0], lds_s[p * 3 + 1], lds_s[p * 3 + 2], o);
                float* __restrict__ lo = lds_o + p * 9;
#pragma unroll
                for (int j = 0; j < 9; ++j) lo[j] = o[j];
            }
        }
        __syncthreads();

        {
            const int nOF = nPts * 9;
            const int nO4 = nOF >> 2;
            f32x4* __restrict__ dst = (f32x4*)(out + tileBase * 9);
            const f32x4* __restrict__ lo4 = (const f32x4*)lds_o;
            for (int i = tid; i < nO4; i += BLK) dst[i] = lo4[i];
            for (int i = (nO4 << 2) + tid; i < nOF; i += BLK)
                out[tileBase * 9 + i] = lds_o[i];
        }
    }
}

extern "C" void kernel_launch(void* const* d_in, const int* in_sizes, int n_in,
                              void* d_out, int out_size, void* d_ws, size_t ws_size,
                              hipStream_t stream) {
    const float* scaling  = (const float*)d_in[0];
    const float* rotation = (const float*)d_in[1];
    float* out = (float*)d_out;
    const int N = in_sizes[0] / 3;
    const int blocks = (N + PTS - 1) / PTS;
    gaussian_cov_kernel<<<blocks, BLK, 0, stream>>>(scaling, rotation, out, N);
}